// Round 5
// baseline (1777.089 us; speedup 1.0000x reference)
//
#include <hip/hip_runtime.h>
#include <math.h>

#define B 128
#define T 1998
#define H 256
#define U 256
#define KTOP 1332
#define BT (B*T)

typedef float v2f __attribute__((ext_vector_type(2)));

// ---------------- workspace layout (float elements) ----------------
#define WS_CONVPART 0
#define WS_SPART    0
#define WS_SIG      (2*BT)
#define WS_DEN      (3*BT)
#define WS_CTXPART  (3*BT + 2048)
#define WS_CONVO    (4*BT)
#define WS_QPROJ    (5*BT)

// ---------------- q_proj = query @ W2^T + b2 ----------------
__global__ void qproj_kernel(const float* __restrict__ query,
                             const float* __restrict__ W2w,
                             const float* __restrict__ W2b,
                             float* __restrict__ qproj) {
    __shared__ __align__(16) float qs[H];
    int b = blockIdx.x;
    int u = threadIdx.x;
    qs[u] = query[b*H + u];
    __syncthreads();
    const float4* w  = (const float4*)(W2w + u*H);
    const float4* q4 = (const float4*)qs;
    float acc = 0.f;
    #pragma unroll 8
    for (int i = 0; i < H/4; ++i) {
        float4 wv = w[i]; float4 qv = q4[i];
        acc = fmaf(wv.x, qv.x, acc); acc = fmaf(wv.y, qv.y, acc);
        acc = fmaf(wv.z, qv.z, acc); acc = fmaf(wv.w, qv.w, acc);
    }
    qproj[b*U + u] = acc + W2b[u];
}

// ---------------- conv: part[c][b][t] = sum_{i in chunk c} prev[b,i]*conv_w[t,i,3] ----------------
#define CT 32
#define CCHUNK 500
__global__ __launch_bounds__(256)
void conv_kernel(const float* __restrict__ prev,
                 const float* __restrict__ convw,
                 float* __restrict__ part) {
    __shared__ __align__(16) float W3s[CT*68];
    __shared__ __align__(16) float Ps[B*68];
    int t0 = blockIdx.x * CT;
    int i_begin = blockIdx.y * CCHUNK;
    int i_end = min(T, i_begin + CCHUNK);
    int tid = threadIdx.x;
    int tx = tid & 7;
    int ty = tid >> 3;
    float acc[4][4] = {};
    for (int i0 = i_begin; i0 < i_end; i0 += 64) {
        int ni = i_end - i0; if (ni > 64) ni = 64;
        #pragma unroll
        for (int r = 0; r < 8; ++r) {
            int idx = tid + 256*r;
            int tl = idx >> 6, il = idx & 63;
            int t = t0 + tl;
            float v = 0.f;
            if (il < ni && t < T) v = convw[((long)t*T + (i0+il))*7 + 3];
            W3s[tl*68 + il] = v;
        }
        #pragma unroll
        for (int r = 0; r < 16; ++r) {
            int idx = tid + 256*r;
            int bl = idx >> 5, i2 = idx & 31;
            int il = i2*2;
            float vx = 0.f, vy = 0.f;
            if (il < ni) {
                if (il + 1 < ni) {
                    float2 v = *(const float2*)(prev + bl*T + i0 + il);
                    vx = v.x; vy = v.y;
                } else vx = prev[bl*T + i0 + il];
            }
            Ps[bl*68 + il] = vx; Ps[bl*68 + il + 1] = vy;
        }
        __syncthreads();
        const float4* W3f = (const float4*)W3s;
        const float4* Pf  = (const float4*)Ps;
        #pragma unroll
        for (int i4 = 0; i4 < 16; ++i4) {
            float4 w4[4], p4[4];
            #pragma unroll
            for (int r = 0; r < 4; ++r) w4[r] = W3f[(tx + 8*r)*17 + i4];
            #pragma unroll
            for (int j = 0; j < 4; ++j) p4[j] = Pf[(ty + 32*j)*17 + i4];
            #pragma unroll
            for (int r = 0; r < 4; ++r)
                #pragma unroll
                for (int j = 0; j < 4; ++j) {
                    float a = acc[r][j];
                    a = fmaf(w4[r].x, p4[j].x, a);
                    a = fmaf(w4[r].y, p4[j].y, a);
                    a = fmaf(w4[r].z, p4[j].z, a);
                    a = fmaf(w4[r].w, p4[j].w, a);
                    acc[r][j] = a;
                }
        }
        __syncthreads();
    }
    int cb = blockIdx.y;
    #pragma unroll
    for (int r = 0; r < 4; ++r) {
        int t = t0 + tx + 8*r;
        if (t < T)
            #pragma unroll
            for (int j = 0; j < 4; ++j)
                part[cb*BT + (ty + 32*j)*T + t] = acc[r][j];
    }
}

__global__ void conv_reduce(const float* __restrict__ part, float* __restrict__ convo) {
    int i = blockIdx.x*256 + threadIdx.x;
    if (i < BT) convo[i] = (part[i] + part[BT+i]) + (part[2*BT+i] + part[3*BT+i]);
}

// ---------------- fused partial score, 128t x 128u tile ----------------
// R5: 8r x 8j register tile (128 v2f-lane accs). Raises FMA:ds_read from
// 64:12 to 128:16 per k4 -> VALU is sole critical pipe (512 issue-cyc vs
// 192 LDS-cyc). NB: v_pk_fma_f32 does NOT double fp32 rate on CDNA4 (157 TF
// counts 1 FMA/lane/cy) - R4's 2x was contraction, packing just saves regs.
__global__ __launch_bounds__(256)
void score_kernel(const float* __restrict__ values, const float* __restrict__ W1w,
                  const float* __restrict__ W1b, const float* __restrict__ Vw,
                  const float* __restrict__ lp,
                  const float* __restrict__ qproj, const float* __restrict__ convo,
                  float* __restrict__ spart) {
    __shared__ __align__(16) float Vs[128*36];     // 128 t x 32 k, stride 36
    __shared__ __align__(16) float W1s[128*36];    // 128 u x 32 k, stride 36
    __shared__ float qpS[128], bS[128], vwS[128], lpS[128];
    int b  = blockIdx.z;
    int u0 = blockIdx.y * 128;
    int t0 = blockIdx.x * 128;
    int tid = threadIdx.x;
    int tx = tid & 15;         // u = u0 + tx + 16j, j<8
    int ty = tid >> 4;         // t = t0 + ty + 16r, r<8
    if (tid < 128) {
        int u = u0 + tid;
        qpS[tid] = qproj[b*U + u];
        bS[tid]  = W1b[u];
        vwS[tid] = Vw[u];
        lpS[tid] = lp[u];
    }
    v2f acc2[8][8];
    #pragma unroll
    for (int r = 0; r < 8; ++r)
        #pragma unroll
        for (int j = 0; j < 8; ++j) { v2f z = {0.f, 0.f}; acc2[r][j] = z; }

    const float4* Vsf = (const float4*)Vs;
    const float4* Wsf = (const float4*)W1s;
    for (int k0 = 0; k0 < H; k0 += 32) {
        __syncthreads();
        #pragma unroll
        for (int r = 0; r < 4; ++r) {              // stage W1 128x32
            int idx = tid + 256*r;
            int u = idx >> 3, f4 = idx & 7;
            float4 v = *(const float4*)(W1w + (u0 + u)*H + k0 + f4*4);
            *(float4*)(W1s + u*36 + f4*4) = v;
        }
        #pragma unroll
        for (int r = 0; r < 4; ++r) {              // stage values 128x32
            int idx = tid + 256*r;
            int row = idx >> 3, f4 = idx & 7;
            int t = t0 + row;
            float4 v = make_float4(0.f,0.f,0.f,0.f);
            if (t < T) v = *(const float4*)(values + ((long)b*T + t)*H + k0 + f4*4);
            *(float4*)(Vs + row*36 + f4*4) = v;
        }
        __syncthreads();
        #pragma unroll
        for (int k4 = 0; k4 < 8; ++k4) {
            v2f vlo[8], vhi[8];
            #pragma unroll
            for (int r = 0; r < 8; ++r) {
                float4 v4 = Vsf[(ty + 16*r)*9 + k4];
                v2f a = {v4.x, v4.y}; v2f c = {v4.z, v4.w};
                vlo[r] = a; vhi[r] = c;
            }
            #pragma unroll
            for (int j = 0; j < 8; ++j) {
                float4 w4 = Wsf[(tx + 16*j)*9 + k4];
                v2f wlo = {w4.x, w4.y};
                v2f whi = {w4.z, w4.w};
                #pragma unroll
                for (int r = 0; r < 8; ++r) {
                    acc2[r][j] = __builtin_elementwise_fma(vlo[r], wlo, acc2[r][j]);
                    acc2[r][j] = __builtin_elementwise_fma(vhi[r], whi, acc2[r][j]);
                }
            }
        }
    }
    #pragma unroll
    for (int r = 0; r < 8; ++r) {
        int t = t0 + ty + 16*r;
        float c = (t < T) ? convo[b*T + t] : 0.f;
        float part = 0.f;
        #pragma unroll
        for (int j = 0; j < 8; ++j) {
            int ul = tx + 16*j;
            float s = (acc2[r][j].x + acc2[r][j].y) + bS[ul] + qpS[ul] + c*lpS[ul];
            part += vwS[ul] * tanhf(s);
        }
        part += __shfl_xor(part, 1);
        part += __shfl_xor(part, 2);
        part += __shfl_xor(part, 4);
        part += __shfl_xor(part, 8);
        if (tx == 0 && t < T) spart[blockIdx.y*BT + b*T + t] = part;
    }
}

// ---------------- per-row exact top-K mask (radix select 11/11/10) + sigmoid ----------------
__device__ inline unsigned int fkey(float f) {
    unsigned int u = __float_as_uint(f);
    return (u & 0x80000000u) ? ~u : (u | 0x80000000u);
}

__global__ void zero_den(float* __restrict__ den) {
    int i = threadIdx.x + blockIdx.x*256;
    if (i < 2048) den[i] = 0.f;
}

__global__ void topk_kernel(const float* __restrict__ spart,
                            const float* __restrict__ Vb,
                            float* __restrict__ out_score,
                            float* __restrict__ sig,
                            float* __restrict__ den) {
    __shared__ float s[T];
    __shared__ unsigned int hist[2048];
    __shared__ int partial[256];
    __shared__ unsigned int sh_bin;
    __shared__ int sh_need;
    int b = blockIdx.x;
    int tid = threadIdx.x;
    float vb = Vb[0];
    for (int t = tid; t < T; t += 256)
        s[t] = spart[b*T + t] + spart[BT + b*T + t] + vb;
    __syncthreads();

    int need = KTOP;
    unsigned int b1 = 0, b2 = 0, b3 = 0;
    for (int pass = 0; pass < 3; ++pass) {
        for (int i = tid; i < 2048; i += 256) hist[i] = 0u;
        __syncthreads();
        for (int t = tid; t < T; t += 256) {
            unsigned int k = fkey(s[t]);
            if (pass == 0) {
                atomicAdd(&hist[k >> 21], 1u);
            } else if (pass == 1) {
                if ((k >> 21) == b1) atomicAdd(&hist[(k >> 10) & 0x7FFu], 1u);
            } else {
                if ((k >> 10) == ((b1 << 11) | b2)) atomicAdd(&hist[k & 0x3FFu], 1u);
            }
        }
        __syncthreads();
        { unsigned int a = 0;
          for (int i = 0; i < 8; ++i) a += hist[tid*8 + i];
          partial[tid] = (int)a; }
        __syncthreads();
        if (tid == 0) {
            int cum = 0, bsel = 0;
            for (int g = 255; g >= 0; --g) {
                if (cum + partial[g] >= need) {
                    for (int bb = g*8 + 7; ; --bb) {
                        if (cum + (int)hist[bb] >= need) { bsel = bb; break; }
                        cum += (int)hist[bb];
                    }
                    sh_bin = (unsigned int)bsel; sh_need = need - cum;
                    break;
                }
                cum += partial[g];
            }
        }
        __syncthreads();
        if (pass == 0) b1 = sh_bin;
        else if (pass == 1) b2 = sh_bin;
        else b3 = sh_bin;
        need = sh_need;
        __syncthreads();
    }
    unsigned int vstar = (b1 << 21) | (b2 << 10) | b3;
    int nt = need;   // #ties at vstar to keep (lowest indices first)

    for (int t = tid; t < T; t += 256) {
        float v = s[t];
        unsigned int k = fkey(v);
        bool keep = (k > vstar);
        if (k == vstar) {
            int rank = 0;
            for (int q = 0; q < t; ++q) if (fkey(s[q]) == vstar) ++rank;
            keep = (rank < nt);
        }
        float m = keep ? v : 0.f;
        out_score[b*T + t] = m;
        float sg = 1.f / (1.f + expf(-m));
        sig[b*T + t] = sg;
        atomicAdd(&den[t], sg);
    }
}

// ---------------- aw[b][t] = sig/den ----------------
__global__ void aw_kernel(const float* __restrict__ sig, const float* __restrict__ den,
                          float* __restrict__ aw) {
    int t = blockIdx.x*256 + threadIdx.x;
    int b = blockIdx.y;
    if (t < T) aw[b*T + t] = sig[b*T + t] / den[t];
}

// ---------------- context partials over t-chunks ----------------
__global__ void ctx_kernel(const float* __restrict__ values, const float* __restrict__ sig,
                           const float* __restrict__ den, float* __restrict__ part) {
    int tc = blockIdx.x, b = blockIdx.y, h = threadIdx.x;
    int tbeg = tc*250, tend = min(T, tbeg + 250);
    float acc = 0.f;
    for (int t = tbeg; t < tend; ++t) {
        float a = sig[b*T + t] / den[t];
        acc = fmaf(a, values[((long)b*T + t)*H + h], acc);
    }
    part[(tc*B + b)*H + h] = acc;
}

__global__ void ctx_reduce(const float* __restrict__ part, float* __restrict__ out0) {
    int b = blockIdx.x, h = threadIdx.x;
    float a = 0.f;
    #pragma unroll
    for (int c = 0; c < 8; ++c) a += part[(c*B + b)*H + h];
    out0[b*H + h] = a;
}

// ---------------- launcher ----------------
extern "C" void kernel_launch(void* const* d_in, const int* in_sizes, int n_in,
                              void* d_out, int out_size, void* d_ws, size_t ws_size,
                              hipStream_t stream) {
    (void)in_sizes; (void)n_in; (void)out_size; (void)ws_size;
    const float* query  = (const float*)d_in[0];
    const float* values = (const float*)d_in[1];
    const float* prev   = (const float*)d_in[2];
    const float* W1w    = (const float*)d_in[3];
    const float* W1b    = (const float*)d_in[4];
    const float* W2w    = (const float*)d_in[5];
    const float* W2b    = (const float*)d_in[6];
    const float* Vw     = (const float*)d_in[7];
    const float* Vb     = (const float*)d_in[8];
    const float* convw  = (const float*)d_in[9];
    const float* lp     = (const float*)d_in[10];

    float* ws = (float*)d_ws;
    float* out0 = (float*)d_out;            // context [B,H]
    float* out1 = out0 + B*H;               // attention_weights [B,T]
    float* out2 = out1 + BT;                // masked score [B,T]

    qproj_kernel<<<dim3(B), 256, 0, stream>>>(query, W2w, W2b, ws + WS_QPROJ);
    conv_kernel<<<dim3(63, 4), 256, 0, stream>>>(prev, convw, ws + WS_CONVPART);
    conv_reduce<<<dim3(999), 256, 0, stream>>>(ws + WS_CONVPART, ws + WS_CONVO);
    zero_den<<<dim3(8), 256, 0, stream>>>(ws + WS_DEN);
    score_kernel<<<dim3(16, 2, B), 256, 0, stream>>>(values, W1w, W1b, Vw, lp,
                                                     ws + WS_QPROJ, ws + WS_CONVO,
                                                     ws + WS_SPART);
    topk_kernel<<<dim3(B), 256, 0, stream>>>(ws + WS_SPART, Vb, out2, ws + WS_SIG,
                                             ws + WS_DEN);
    aw_kernel<<<dim3(8, B), 256, 0, stream>>>(ws + WS_SIG, ws + WS_DEN, out1);
    ctx_kernel<<<dim3(8, B), 256, 0, stream>>>(values, ws + WS_SIG, ws + WS_DEN,
                                               ws + WS_CTXPART);
    ctx_reduce<<<dim3(B), 256, 0, stream>>>(ws + WS_CTXPART, out0);
}

// Round 6
// 1168.566 us; speedup vs baseline: 1.5207x; 1.5207x over previous
//
#include <hip/hip_runtime.h>
#include <math.h>

#define B 128
#define T 1998
#define H 256
#define U 256
#define KTOP 1332
#define BT (B*T)
#define TT 16            // t-tiles of 128 (16*128 = 2048 >= 1998)

typedef __attribute__((ext_vector_type(8))) short short8;   // 8 bf16 (4 VGPRs)
typedef __attribute__((ext_vector_type(4))) float f32x4;    // MFMA C/D

// ---------------- workspace layout (float elements) ----------------
#define WS_SCORE    0
#define WS_CONVPART 0
#define WS_SIG      (2*BT)
#define WS_DEN      (3*BT)
#define WS_CTXPART  (3*BT + 2048)
#define WS_CONVO    (4*BT)
#define WS_QPROJ    (5*BT)
#define WS_WH       (5*BT + B*U)             // ushort[65536] = 32768 floats
#define WS_WL       (5*BT + B*U + 32768)     // ushort[65536]

// bf16 RNE split: hi = bf16(x), returns hi bits; hif = hi as f32
__device__ inline unsigned short bf16_rne(float x, float* hif) {
    unsigned ub = __float_as_uint(x);
    unsigned r1 = ub + 0x7FFFu + ((ub >> 16) & 1u);
    *hif = __uint_as_float(r1 & 0xFFFF0000u);
    return (unsigned short)(r1 >> 16);
}

__device__ inline float fast_tanh(float x) {
    x = fminf(15.f, fmaxf(-15.f, x));
    float e = __expf(-2.f * x);
    return __fdividef(1.f - e, 1.f + e);
}

// ---------------- q_proj = query @ W2^T + b2 ----------------
__global__ void qproj_kernel(const float* __restrict__ query,
                             const float* __restrict__ W2w,
                             const float* __restrict__ W2b,
                             float* __restrict__ qproj) {
    __shared__ __align__(16) float qs[H];
    int b = blockIdx.x;
    int u = threadIdx.x;
    qs[u] = query[b*H + u];
    __syncthreads();
    const float4* w  = (const float4*)(W2w + u*H);
    const float4* q4 = (const float4*)qs;
    float acc = 0.f;
    #pragma unroll 8
    for (int i = 0; i < H/4; ++i) {
        float4 wv = w[i]; float4 qv = q4[i];
        acc = fmaf(wv.x, qv.x, acc); acc = fmaf(wv.y, qv.y, acc);
        acc = fmaf(wv.z, qv.z, acc); acc = fmaf(wv.w, qv.w, acc);
    }
    qproj[b*U + u] = acc + W2b[u];
}

// ---------------- W1 bf16 hi/lo split (tiny, precomputed once) ----------------
__global__ void wsplit_kernel(const float* __restrict__ W1w,
                              unsigned short* __restrict__ Wh,
                              unsigned short* __restrict__ Wl) {
    int i = blockIdx.x*256 + threadIdx.x;
    if (i < U*H) {
        float x = W1w[i], hif;
        unsigned short h = bf16_rne(x, &hif);
        float lo = x - hif, dummy;
        unsigned short l = bf16_rne(lo, &dummy);
        Wh[i] = h; Wl[i] = l;
    }
}

// ---------------- conv: part[c][b][t] = sum_{i in chunk c} prev[b,i]*conv_w[t,i,3] ----------------
#define CT 32
#define CCHUNK 500
__global__ __launch_bounds__(256)
void conv_kernel(const float* __restrict__ prev,
                 const float* __restrict__ convw,
                 float* __restrict__ part) {
    __shared__ __align__(16) float W3s[CT*68];
    __shared__ __align__(16) float Ps[B*68];
    int t0 = blockIdx.x * CT;
    int i_begin = blockIdx.y * CCHUNK;
    int i_end = min(T, i_begin + CCHUNK);
    int tid = threadIdx.x;
    int tx = tid & 7;
    int ty = tid >> 3;
    float acc[4][4] = {};
    for (int i0 = i_begin; i0 < i_end; i0 += 64) {
        int ni = i_end - i0; if (ni > 64) ni = 64;
        #pragma unroll
        for (int r = 0; r < 8; ++r) {
            int idx = tid + 256*r;
            int tl = idx >> 6, il = idx & 63;
            int t = t0 + tl;
            float v = 0.f;
            if (il < ni && t < T) v = convw[((long)t*T + (i0+il))*7 + 3];
            W3s[tl*68 + il] = v;
        }
        #pragma unroll
        for (int r = 0; r < 16; ++r) {
            int idx = tid + 256*r;
            int bl = idx >> 5, i2 = idx & 31;
            int il = i2*2;
            float vx = 0.f, vy = 0.f;
            if (il < ni) {
                if (il + 1 < ni) {
                    float2 v = *(const float2*)(prev + bl*T + i0 + il);
                    vx = v.x; vy = v.y;
                } else vx = prev[bl*T + i0 + il];
            }
            Ps[bl*68 + il] = vx; Ps[bl*68 + il + 1] = vy;
        }
        __syncthreads();
        const float4* W3f = (const float4*)W3s;
        const float4* Pf  = (const float4*)Ps;
        #pragma unroll
        for (int i4 = 0; i4 < 16; ++i4) {
            float4 w4[4], p4[4];
            #pragma unroll
            for (int r = 0; r < 4; ++r) w4[r] = W3f[(tx + 8*r)*17 + i4];
            #pragma unroll
            for (int j = 0; j < 4; ++j) p4[j] = Pf[(ty + 32*j)*17 + i4];
            #pragma unroll
            for (int r = 0; r < 4; ++r)
                #pragma unroll
                for (int j = 0; j < 4; ++j) {
                    float a = acc[r][j];
                    a = fmaf(w4[r].x, p4[j].x, a);
                    a = fmaf(w4[r].y, p4[j].y, a);
                    a = fmaf(w4[r].z, p4[j].z, a);
                    a = fmaf(w4[r].w, p4[j].w, a);
                    acc[r][j] = a;
                }
        }
        __syncthreads();
    }
    int cb = blockIdx.y;
    #pragma unroll
    for (int r = 0; r < 4; ++r) {
        int t = t0 + tx + 8*r;
        if (t < T)
            #pragma unroll
            for (int j = 0; j < 4; ++j)
                part[cb*BT + (ty + 32*j)*T + t] = acc[r][j];
    }
}

__global__ void conv_reduce(const float* __restrict__ part, float* __restrict__ convo) {
    int i = blockIdx.x*256 + threadIdx.x;
    if (i < BT) convo[i] = (part[i] + part[BT+i]) + (part[2*BT+i] + part[3*BT+i]);
}

// ---------------- MFMA split-bf16 score: 128t x 256u per block ----------------
// 3-term split GEMM: e = Vh*Wh + Vh*Wl + Vl*Wh (fp32 acc). Error ~2-6e-5
// per score; top-K boundary fixed by exact fp32 rescoring in topk.
// 16x16x32_bf16: A[m=lane&15][k=(lane>>4)*8+j]; B[k][n=lane&15] mirrored;
// D: col=lane&15, row=(lane>>4)*4+reg  (HW-verified mappings).
__global__ __launch_bounds__(256)
void score_mfma(const float* __restrict__ values,
                const unsigned short* __restrict__ Wh,
                const unsigned short* __restrict__ Wl,
                const float* __restrict__ W1b, const float* __restrict__ Vw,
                const float* __restrict__ Vb,  const float* __restrict__ lp,
                const float* __restrict__ qproj, const float* __restrict__ convo,
                float* __restrict__ score) {
    __shared__ __align__(16) unsigned short AhS[128*40];  // 80B rows: 2-way-max banks
    __shared__ __align__(16) unsigned short AlS[128*40];
    __shared__ __align__(16) unsigned short BhS[256*40];
    __shared__ __align__(16) unsigned short BlS[256*40];
    __shared__ float conS[128];
    __shared__ float bqS[256], vwS[256], lpS[256];
    __shared__ float sred[128];

    int b  = blockIdx.y;
    int t0 = blockIdx.x * 128;
    int tid = threadIdx.x;
    int wid = tid >> 6, lane = tid & 63;
    int th = wid & 1;          // t-half (64 rows)
    int uh = wid >> 1;         // u-half (128 cols)
    int ml = lane & 15;
    int q  = lane >> 4;

    if (tid < 128) {
        int t = t0 + tid;
        conS[tid] = (t < T) ? convo[b*T + t] : 0.f;
    }
    bqS[tid] = W1b[tid] + qproj[b*U + tid];
    vwS[tid] = Vw[tid];
    lpS[tid] = lp[tid];

    f32x4 acc[4][8];
    #pragma unroll
    for (int mt = 0; mt < 4; ++mt)
        #pragma unroll
        for (int nt = 0; nt < 8; ++nt) { f32x4 z = {0.f,0.f,0.f,0.f}; acc[mt][nt] = z; }

    for (int s = 0; s < 8; ++s) {
        __syncthreads();
        // stage A (values fp32 -> bf16 hi/lo), 512 chunk-jobs
        #pragma unroll
        for (int r = 0; r < 2; ++r) {
            int c = r*256 + tid;
            int row = c >> 2, qq = c & 3;
            int t = t0 + row;
            float xs[8] = {0,0,0,0,0,0,0,0};
            if (t < T) {
                const float* src = values + ((long)(b*T + t))*H + s*32 + qq*8;
                *(float4*)&xs[0] = *(const float4*)src;
                *(float4*)&xs[4] = *(const float4*)(src + 4);
            }
            union { unsigned short u[8]; short8 v; } Hh, Ll;
            #pragma unroll
            for (int e = 0; e < 8; ++e) {
                float hif, d2;
                Hh.u[e] = bf16_rne(xs[e], &hif);
                Ll.u[e] = bf16_rne(xs[e] - hif, &d2);
            }
            *(short8*)(&AhS[row*40 + qq*8]) = Hh.v;
            *(short8*)(&AlS[row*40 + qq*8]) = Ll.v;
        }
        // stage B hi (bf16 copy), 1024 jobs
        #pragma unroll
        for (int r = 0; r < 4; ++r) {
            int c = r*256 + tid;
            int row = c >> 2, qq = c & 3;
            short8 v = *(const short8*)(Wh + row*H + s*32 + qq*8);
            *(short8*)(&BhS[row*40 + qq*8]) = v;
        }
        // stage B lo
        #pragma unroll
        for (int r = 0; r < 4; ++r) {
            int c = r*256 + tid;
            int row = c >> 2, qq = c & 3;
            short8 v = *(const short8*)(Wl + row*H + s*32 + qq*8);
            *(short8*)(&BlS[row*40 + qq*8]) = v;
        }
        __syncthreads();

        short8 ah[4], al[4];
        #pragma unroll
        for (int mt = 0; mt < 4; ++mt) {
            int row = th*64 + mt*16 + ml;
            ah[mt] = *(const short8*)(&AhS[row*40 + q*8]);
            al[mt] = *(const short8*)(&AlS[row*40 + q*8]);
        }
        #pragma unroll
        for (int nt = 0; nt < 8; ++nt) {
            int urow = uh*128 + nt*16 + ml;
            short8 bh = *(const short8*)(&BhS[urow*40 + q*8]);
            short8 bl = *(const short8*)(&BlS[urow*40 + q*8]);
            #pragma unroll
            for (int mt = 0; mt < 4; ++mt) {
                acc[mt][nt] = __builtin_amdgcn_mfma_f32_16x16x32_bf16(ah[mt], bh, acc[mt][nt], 0, 0, 0);
                acc[mt][nt] = __builtin_amdgcn_mfma_f32_16x16x32_bf16(al[mt], bh, acc[mt][nt], 0, 0, 0);
                acc[mt][nt] = __builtin_amdgcn_mfma_f32_16x16x32_bf16(ah[mt], bl, acc[mt][nt], 0, 0, 0);
            }
        }
    }

    // epilogue: e = acc + (b+qp)[u] + convo*lp[u]; psum_u vw*tanh(e)
    float vb = Vb[0];
    float psv[4][4];
    #pragma unroll
    for (int mt = 0; mt < 4; ++mt) {
        #pragma unroll
        for (int i = 0; i < 4; ++i) {
            int tl = th*64 + mt*16 + q*4 + i;
            float c = conS[tl];
            float ps = 0.f;
            #pragma unroll
            for (int nt = 0; nt < 8; ++nt) {
                int ul = uh*128 + nt*16 + ml;
                float e = acc[mt][nt][i] + bqS[ul] + c*lpS[ul];
                ps += vwS[ul] * fast_tanh(e);
            }
            ps += __shfl_xor(ps, 1);
            ps += __shfl_xor(ps, 2);
            ps += __shfl_xor(ps, 4);
            ps += __shfl_xor(ps, 8);
            psv[mt][i] = ps;   // valid at ml==0 lanes of each quad
        }
    }
    // cross-wave u-half combine via LDS
    if (uh == 0 && ml == 0) {
        #pragma unroll
        for (int mt = 0; mt < 4; ++mt)
            #pragma unroll
            for (int i = 0; i < 4; ++i)
                sred[th*64 + mt*16 + q*4 + i] = psv[mt][i];
    }
    __syncthreads();
    if (uh == 1 && ml == 0) {
        #pragma unroll
        for (int mt = 0; mt < 4; ++mt)
            #pragma unroll
            for (int i = 0; i < 4; ++i) {
                int tl = th*64 + mt*16 + q*4 + i;
                int t = t0 + tl;
                if (t < T) score[b*T + t] = sred[tl] + psv[mt][i] + vb;
            }
    }
}

// ---------------- topk: select on MFMA scores, exact-fp32 boundary rescore,
// re-select, mask + sigmoid + den ----------------
__device__ inline unsigned int fkey(float f) {
    unsigned int u = __float_as_uint(f);
    return (u & 0x80000000u) ? ~u : (u | 0x80000000u);
}

#define DELTA 4e-3f
#define CANDMAX 128

__global__ void zero_den(float* __restrict__ den) {
    int i = threadIdx.x + blockIdx.x*256;
    if (i < 2048) den[i] = 0.f;
}

__global__ __launch_bounds__(256)
void topk_kernel(const float* __restrict__ score,
                 const float* __restrict__ values,
                 const float* __restrict__ W1w,
                 const float* __restrict__ W1b,
                 const float* __restrict__ Vw,
                 const float* __restrict__ Vb,
                 const float* __restrict__ qproj,
                 const float* __restrict__ convo,
                 const float* __restrict__ lp,
                 float* __restrict__ out_score,
                 float* __restrict__ sig,
                 float* __restrict__ den) {
    __shared__ float s[T];
    __shared__ unsigned int hist[2048];
    __shared__ int partial[256];
    __shared__ unsigned int sh_bin;
    __shared__ int sh_need;
    __shared__ int sh_ncand;
    __shared__ int cand[CANDMAX];
    __shared__ __align__(16) float vrow[H];
    __shared__ float wred[4];
    int b = blockIdx.x;
    int tid = threadIdx.x;
    float vb = Vb[0];
    for (int t = tid; t < T; t += 256) s[t] = score[b*T + t];
    if (tid == 0) sh_ncand = 0;
    __syncthreads();

    unsigned int vstar = 0; int nt = 0;
    for (int round = 0; round < 2; ++round) {
        int need = KTOP;
        unsigned int b1 = 0, b2 = 0;
        for (int pass = 0; pass < 3; ++pass) {
            for (int i = tid; i < 2048; i += 256) hist[i] = 0u;
            __syncthreads();
            for (int t = tid; t < T; t += 256) {
                unsigned int k = fkey(s[t]);
                if (pass == 0) {
                    atomicAdd(&hist[k >> 21], 1u);
                } else if (pass == 1) {
                    if ((k >> 21) == b1) atomicAdd(&hist[(k >> 10) & 0x7FFu], 1u);
                } else {
                    if ((k >> 10) == ((b1 << 11) | b2)) atomicAdd(&hist[k & 0x3FFu], 1u);
                }
            }
            __syncthreads();
            { unsigned int a = 0;
              for (int i = 0; i < 8; ++i) a += hist[tid*8 + i];
              partial[tid] = (int)a; }
            __syncthreads();
            if (tid == 0) {
                int cum = 0, bsel = 0;
                for (int g = 255; g >= 0; --g) {
                    if (cum + partial[g] >= need) {
                        for (int bb = g*8 + 7; ; --bb) {
                            if (cum + (int)hist[bb] >= need) { bsel = bb; break; }
                            cum += (int)hist[bb];
                        }
                        sh_bin = (unsigned int)bsel; sh_need = need - cum;
                        break;
                    }
                    cum += partial[g];
                }
            }
            __syncthreads();
            if (pass == 0) b1 = sh_bin;
            else if (pass == 1) b2 = sh_bin;
            need = sh_need;
            __syncthreads();
        }
        vstar = (b1 << 21) | (b2 << 11) | sh_bin;   // NOTE: pass1 yields 11 bits
        // careful: b2 holds 11 bits (pass1), pass2 10 bits
        vstar = (b1 << 21) | (b2 << 10) | sh_bin;
        nt = sh_need;

        if (round == 0) {
            // reconstruct threshold float, collect boundary candidates
            unsigned int k = vstar;
            unsigned int ub = (k & 0x80000000u) ? (k & 0x7FFFFFFFu) : ~k;
            float vf = __uint_as_float(ub);
            for (int t = tid; t < T; t += 256) {
                if (fabsf(s[t] - vf) <= DELTA) {
                    int idx = atomicAdd(&sh_ncand, 1);
                    if (idx < CANDMAX) cand[idx] = t;
                }
            }
            __syncthreads();
            int m = sh_ncand; if (m > CANDMAX) m = CANDMAX;
            for (int ci = 0; ci < m; ++ci) {
                int tc = cand[ci];
                vrow[tid] = values[((long)(b*T + tc))*H + tid];
                __syncthreads();
                // exact fp32 rescore: thread = u
                const float4* w4 = (const float4*)(W1w + (long)tid*H);
                const float4* v4 = (const float4*)vrow;
                float accd = 0.f;
                #pragma unroll 8
                for (int i = 0; i < H/4; ++i) {
                    float4 a = v4[i], w = w4[i];
                    accd = fmaf(a.x, w.x, accd); accd = fmaf(a.y, w.y, accd);
                    accd = fmaf(a.z, w.z, accd); accd = fmaf(a.w, w.w, accd);
                }
                float ct = convo[b*T + tc];
                float e = accd + W1b[tid] + qproj[b*U + tid] + ct*lp[tid];
                float ps = Vw[tid] * tanhf(e);
                #pragma unroll
                for (int o = 1; o < 64; o <<= 1) ps += __shfl_xor(ps, o);
                if ((tid & 63) == 0) wred[tid >> 6] = ps;
                __syncthreads();
                if (tid == 0) s[tc] = (wred[0] + wred[1]) + (wred[2] + wred[3]) + vb;
                __syncthreads();
            }
        }
    }

    // final mask with exact tie handling (lowest indices kept first)
    for (int t = tid; t < T; t += 256) {
        float v = s[t];
        unsigned int k = fkey(v);
        bool keep = (k > vstar);
        if (k == vstar) {
            int rank = 0;
            for (int qx = 0; qx < t; ++qx) if (fkey(s[qx]) == vstar) ++rank;
            keep = (rank < nt);
        }
        float m = keep ? v : 0.f;
        out_score[b*T + t] = m;
        float sg = 1.f / (1.f + expf(-m));
        sig[b*T + t] = sg;
        atomicAdd(&den[t], sg);
    }
}

// ---------------- aw[b][t] = sig/den ----------------
__global__ void aw_kernel(const float* __restrict__ sig, const float* __restrict__ den,
                          float* __restrict__ aw) {
    int t = blockIdx.x*256 + threadIdx.x;
    int b = blockIdx.y;
    if (t < T) aw[b*T + t] = sig[b*T + t] / den[t];
}

// ---------------- context partials over t-chunks ----------------
__global__ void ctx_kernel(const float* __restrict__ values, const float* __restrict__ sig,
                           const float* __restrict__ den, float* __restrict__ part) {
    int tc = blockIdx.x, b = blockIdx.y, h = threadIdx.x;
    int tbeg = tc*250, tend = min(T, tbeg + 250);
    float acc = 0.f;
    for (int t = tbeg; t < tend; ++t) {
        float a = sig[b*T + t] / den[t];
        acc = fmaf(a, values[((long)b*T + t)*H + h], acc);
    }
    part[(tc*B + b)*H + h] = acc;
}

__global__ void ctx_reduce(const float* __restrict__ part, float* __restrict__ out0) {
    int b = blockIdx.x, h = threadIdx.x;
    float a = 0.f;
    #pragma unroll
    for (int c = 0; c < 8; ++c) a += part[(c*B + b)*H + h];
    out0[b*H + h] = a;
}

// ---------------- launcher ----------------
extern "C" void kernel_launch(void* const* d_in, const int* in_sizes, int n_in,
                              void* d_out, int out_size, void* d_ws, size_t ws_size,
                              hipStream_t stream) {
    (void)in_sizes; (void)n_in; (void)out_size; (void)ws_size;
    const float* query  = (const float*)d_in[0];
    const float* values = (const float*)d_in[1];
    const float* prev   = (const float*)d_in[2];
    const float* W1w    = (const float*)d_in[3];
    const float* W1b    = (const float*)d_in[4];
    const float* W2w    = (const float*)d_in[5];
    const float* W2b    = (const float*)d_in[6];
    const float* Vw     = (const float*)d_in[7];
    const float* Vb     = (const float*)d_in[8];
    const float* convw  = (const float*)d_in[9];
    const float* lp     = (const float*)d_in[10];

    float* ws = (float*)d_ws;
    float* out0 = (float*)d_out;            // context [B,H]
    float* out1 = out0 + B*H;               // attention_weights [B,T]
    float* out2 = out1 + BT;                // masked score [B,T]
    unsigned short* Wh = (unsigned short*)(ws + WS_WH);
    unsigned short* Wl = (unsigned short*)(ws + WS_WL);

    qproj_kernel<<<dim3(B), 256, 0, stream>>>(query, W2w, W2b, ws + WS_QPROJ);
    wsplit_kernel<<<dim3((U*H + 255)/256), 256, 0, stream>>>(W1w, Wh, Wl);
    conv_kernel<<<dim3(63, 4), 256, 0, stream>>>(prev, convw, ws + WS_CONVPART);
    conv_reduce<<<dim3(999), 256, 0, stream>>>(ws + WS_CONVPART, ws + WS_CONVO);
    zero_den<<<dim3(8), 256, 0, stream>>>(ws + WS_DEN);
    score_mfma<<<dim3(TT, B), 256, 0, stream>>>(values, Wh, Wl, W1b, Vw, Vb, lp,
                                                ws + WS_QPROJ, ws + WS_CONVO,
                                                ws + WS_SCORE);
    topk_kernel<<<dim3(B), 256, 0, stream>>>(ws + WS_SCORE, values, W1w, W1b, Vw, Vb,
                                             ws + WS_QPROJ, ws + WS_CONVO, lp,
                                             out2, ws + WS_SIG, ws + WS_DEN);
    aw_kernel<<<dim3(8, B), 256, 0, stream>>>(ws + WS_SIG, ws + WS_DEN, out1);
    ctx_kernel<<<dim3(8, B), 256, 0, stream>>>(values, ws + WS_SIG, ws + WS_DEN,
                                               ws + WS_CTXPART);
    ctx_reduce<<<dim3(B), 256, 0, stream>>>(ws + WS_CTXPART, out0);
}